// Round 5
// baseline (178.865 us; speedup 1.0000x reference)
//
#include <hip/hip_runtime.h>

#define TPB 256

__device__ __forceinline__ float frcp(float x) { return __builtin_amdgcn_rcpf(x); }

// Exact Pade(7,6) tanh from the continued fraction:
// tanh(x) = x(135135 + 17325u + 378u^2 + u^3) / (135135 + 62370u + 3150u^2 + 28u^3)
// err <= 1e-4 for |x|<=5 (clamped). Produces N, D separately so rcp can be shared.
__device__ __forceinline__ void tanh_nd(float x, float& N, float& D) {
  x = fminf(fmaxf(x, -5.0f), 5.0f);
  float u = x * x;
  float n = u + 378.0f;
  n = fmaf(n, u, 17325.0f);
  n = fmaf(n, u, 135135.0f);
  N = n * x;
  float d = fmaf(28.0f, u, 3150.0f);
  d = fmaf(d, u, 62370.0f);
  D = fmaf(d, u, 135135.0f);
}

// Two tanh with one shared v_rcp.
__device__ __forceinline__ void tanh2(float x0, float x1, float& t0, float& t1) {
  float N0, D0, N1, D1;
  tanh_nd(x0, N0, D0);
  tanh_nd(x1, N1, D1);
  float r = frcp(D0 * D1);
  t0 = N0 * D1 * r;
  t1 = N1 * D0 * r;
}

// GRU weights with 0.5-folding:
// r,z gate weights/biases pre-scaled by 0.5 (sigmoid(a) = 0.5 + 0.5*tanh(a/2));
// n-gate hidden-side (whh row 4,5 + bhh) pre-scaled by 0.5 so
// r*ghn = ghn' + t_r*ghn' with ghn' = 0.5*ghn.
struct GruW {
  float wr0, wr1, wr2, wr3;   // 0.5 * wih rows 0,1
  float wz0, wz1, wz2, wz3;   // 0.5 * wih rows 2,3
  float wn0, wn1, wn2, wn3;   // wih rows 4,5 (full)
  float ur0, ur1, ur2, ur3;   // 0.5 * whh rows 0,1
  float uz0, uz1, uz2, uz3;   // 0.5 * whh rows 2,3
  float un0, un1, un2, un3;   // 0.5 * whh rows 4,5
  float br0, br1, bz0, bz1;   // 0.5 * (bih+bhh) for r,z
  float bin0, bin1;           // bih n (full)
  float bhn0, bhn1;           // 0.5 * bhh n
};

__device__ __forceinline__ GruW load_gru(const float* __restrict__ wih,
                                         const float* __restrict__ whh,
                                         const float* __restrict__ bih,
                                         const float* __restrict__ bhh) {
  GruW g;
  g.wr0 = 0.5f * wih[0];  g.wr1 = 0.5f * wih[1];
  g.wr2 = 0.5f * wih[2];  g.wr3 = 0.5f * wih[3];
  g.wz0 = 0.5f * wih[4];  g.wz1 = 0.5f * wih[5];
  g.wz2 = 0.5f * wih[6];  g.wz3 = 0.5f * wih[7];
  g.wn0 = wih[8];         g.wn1 = wih[9];
  g.wn2 = wih[10];        g.wn3 = wih[11];
  g.ur0 = 0.5f * whh[0];  g.ur1 = 0.5f * whh[1];
  g.ur2 = 0.5f * whh[2];  g.ur3 = 0.5f * whh[3];
  g.uz0 = 0.5f * whh[4];  g.uz1 = 0.5f * whh[5];
  g.uz2 = 0.5f * whh[6];  g.uz3 = 0.5f * whh[7];
  g.un0 = 0.5f * whh[8];  g.un1 = 0.5f * whh[9];
  g.un2 = 0.5f * whh[10]; g.un3 = 0.5f * whh[11];
  g.br0 = 0.5f * (bih[0] + bhh[0]); g.br1 = 0.5f * (bih[1] + bhh[1]);
  g.bz0 = 0.5f * (bih[2] + bhh[2]); g.bz1 = 0.5f * (bih[3] + bhh[3]);
  g.bin0 = bih[4]; g.bin1 = bih[5];
  g.bhn0 = 0.5f * bhh[4]; g.bhn1 = 0.5f * bhh[5];
  return g;
}

__device__ __forceinline__ void cell(const GruW& g, float x0, float x1,
                                     float& h0, float& h1) {
  // half-scaled r,z pre-activations
  float qr0 = fmaf(g.wr0, x0, fmaf(g.wr1, x1, fmaf(g.ur0, h0, fmaf(g.ur1, h1, g.br0))));
  float qr1 = fmaf(g.wr2, x0, fmaf(g.wr3, x1, fmaf(g.ur2, h0, fmaf(g.ur3, h1, g.br1))));
  float qz0 = fmaf(g.wz0, x0, fmaf(g.wz1, x1, fmaf(g.uz0, h0, fmaf(g.uz1, h1, g.bz0))));
  float qz1 = fmaf(g.wz2, x0, fmaf(g.wz3, x1, fmaf(g.uz2, h0, fmaf(g.uz3, h1, g.bz1))));
  float tr0, tr1, tz0, tz1;
  tanh2(qr0, qr1, tr0, tr1);  // r = 0.5 + 0.5*tr
  tanh2(qz0, qz1, tz0, tz1);  // z = 0.5 + 0.5*tz

  float gin0 = fmaf(g.wn0, x0, fmaf(g.wn1, x1, g.bin0));
  float gin1 = fmaf(g.wn2, x0, fmaf(g.wn3, x1, g.bin1));
  float ghp0 = fmaf(g.un0, h0, fmaf(g.un1, h1, g.bhn0));  // 0.5*ghn
  float ghp1 = fmaf(g.un2, h0, fmaf(g.un3, h1, g.bhn1));
  // n pre-act = gin + r*ghn = (gin + ghp) + tr*ghp
  float an0 = fmaf(tr0, ghp0, gin0 + ghp0);
  float an1 = fmaf(tr1, ghp1, gin1 + ghp1);
  float n0, n1;
  tanh2(an0, an1, n0, n1);

  // h = (1-z)n + z h = n + z(h-n); z = 0.5+0.5tz -> h = (n+d) + tz*d, d = 0.5(h-n)
  float d0 = 0.5f * (h0 - n0);
  float d1 = 0.5f * (h1 - n1);
  h0 = fmaf(tz0, d0, n0 + d0);
  h1 = fmaf(tz1, d1, n1 + d1);
}

__global__ __launch_bounds__(TPB, 8) void rec_policy_kernel(
    const float* __restrict__ x,
    const float* __restrict__ up_wih, const float* __restrict__ up_whh,
    const float* __restrict__ up_bih, const float* __restrict__ up_bhh,
    const float* __restrict__ down_wih, const float* __restrict__ down_whh,
    const float* __restrict__ down_bih, const float* __restrict__ down_bhh,
    const float* __restrict__ obs_w, const float* __restrict__ obs_b,
    const float* __restrict__ out_w, const float* __restrict__ out_b,
    float* __restrict__ out, int B) {
  const long row = (long)blockIdx.x * TPB + threadIdx.x;
  if (row >= B) return;

  // Uniform weight loads -> SGPRs (pre-scaled per the 0.5-folds).
  const GruW up = load_gru(up_wih, up_whh, up_bih, up_bhh);
  const GruW dn = load_gru(down_wih, down_whh, down_bih, down_bhh);
  const float ow0 = obs_w[0], ow1 = obs_w[1], ow2 = obs_w[2], ow3 = obs_w[3],
              ow4 = obs_w[4], ow5 = obs_w[5], ow6 = obs_w[6], ow7 = obs_w[7],
              ow8 = obs_w[8], ow9 = obs_w[9], ow10 = obs_w[10], ow11 = obs_w[11],
              ow12 = obs_w[12], ow13 = obs_w[13];
  const float ob0 = obs_b[0], ob1 = obs_b[1];
  const float vw0 = out_w[0], vw1 = out_w[1], vb = out_b[0];

  // Direct row load: 19 adjacent dwords -> backend merges into dwordx4s.
  const float* __restrict__ xp = x + row * 19;
  float xr0 = xp[0],  xr1 = xp[1],  xr2 = xp[2],  xr3 = xp[3],  xr4 = xp[4];
  float xr5 = xp[5],  xr6 = xp[6],  xr7 = xp[7],  xr8 = xp[8],  xr9 = xp[9];
  float xr10 = xp[10], xr11 = xp[11], xr12 = xp[12], xr13 = xp[13];
  float xr14 = xp[14], xr15 = xp[15], xr16 = xp[16], xr17 = xp[17], xr18 = xp[18];

  // ---- up GRU, 7 steps ----
  float h0 = 0.f, h1 = 0.f;
  float hu0, hu1, hu2, hu3, hu4, hu5, hu6, hu7, hu8, hu9, hu10, hu11, hu12, hu13;
  cell(up, xr5,  xr12, h0, h1); hu0 = h0;  hu1 = h1;
  cell(up, xr6,  xr13, h0, h1); hu2 = h0;  hu3 = h1;
  cell(up, xr7,  xr14, h0, h1); hu4 = h0;  hu5 = h1;
  cell(up, xr8,  xr15, h0, h1); hu6 = h0;  hu7 = h1;
  cell(up, xr9,  xr16, h0, h1); hu8 = h0;  hu9 = h1;
  cell(up, xr10, xr17, h0, h1); hu10 = h0; hu11 = h1;
  cell(up, xr11, xr18, h0, h1); hu12 = h0; hu13 = h1;

  // ---- obs linear ----
  float a0 = fmaf(xr0, ow0, fmaf(xr1, ow1, fmaf(xr2, ow2, fmaf(xr3, ow3,
             fmaf(xr4, ow4, fmaf(hu12, ow5, fmaf(hu13, ow6, ob0)))))));
  float a1 = fmaf(xr0, ow7, fmaf(xr1, ow8, fmaf(xr2, ow9, fmaf(xr3, ow10,
             fmaf(xr4, ow11, fmaf(hu12, ow12, fmaf(hu13, ow13, ob1)))))));
  h0 = a0; h1 = a1;

  // ---- down GRU, 7 steps + per-step output ----
  float* __restrict__ po = out + row * 7;
  float o0, o1, o2, o3, o4, o5, o6;
  cell(dn, hu0,  hu1,  h0, h1); o0 = fmaf(vw0, h0, fmaf(vw1, h1, vb));
  cell(dn, hu2,  hu3,  h0, h1); o1 = fmaf(vw0, h0, fmaf(vw1, h1, vb));
  cell(dn, hu4,  hu5,  h0, h1); o2 = fmaf(vw0, h0, fmaf(vw1, h1, vb));
  cell(dn, hu6,  hu7,  h0, h1); o3 = fmaf(vw0, h0, fmaf(vw1, h1, vb));
  cell(dn, hu8,  hu9,  h0, h1); o4 = fmaf(vw0, h0, fmaf(vw1, h1, vb));
  cell(dn, hu10, hu11, h0, h1); o5 = fmaf(vw0, h0, fmaf(vw1, h1, vb));
  cell(dn, hu12, hu13, h0, h1); o6 = fmaf(vw0, h0, fmaf(vw1, h1, vb));
  po[0] = o0; po[1] = o1; po[2] = o2; po[3] = o3;
  po[4] = o4; po[5] = o5; po[6] = o6;
}

extern "C" void kernel_launch(void* const* d_in, const int* in_sizes, int n_in,
                              void* d_out, int out_size, void* d_ws, size_t ws_size,
                              hipStream_t stream) {
  const float* x        = (const float*)d_in[0];
  const float* up_wih   = (const float*)d_in[1];
  const float* up_whh   = (const float*)d_in[2];
  const float* up_bih   = (const float*)d_in[3];
  const float* up_bhh   = (const float*)d_in[4];
  const float* down_wih = (const float*)d_in[5];
  const float* down_whh = (const float*)d_in[6];
  const float* down_bih = (const float*)d_in[7];
  const float* down_bhh = (const float*)d_in[8];
  const float* obs_w    = (const float*)d_in[9];
  const float* obs_b    = (const float*)d_in[10];
  const float* out_w    = (const float*)d_in[11];
  const float* out_b    = (const float*)d_in[12];
  float* out = (float*)d_out;

  const int B = in_sizes[0] / 19;
  const int blocks = (B + TPB - 1) / TPB;
  rec_policy_kernel<<<blocks, TPB, 0, stream>>>(
      x, up_wih, up_whh, up_bih, up_bhh, down_wih, down_whh, down_bih, down_bhh,
      obs_w, obs_b, out_w, out_b, out, B);
}

// Round 6
// 162.027 us; speedup vs baseline: 1.1039x; 1.1039x over previous
//
#include <hip/hip_runtime.h>

#define TPB 256

__device__ __forceinline__ float ex2(float x) { return __builtin_amdgcn_exp2f(x); }
__device__ __forceinline__ float frcp(float x) { return __builtin_amdgcn_rcpf(x); }

// GRU weights with all activation scale-constants pre-folded:
//  - r,z rows (wih/whh rows 0..3, biases 0..3) scaled by -log2(e):
//      sigmoid(a) = rcp(1 + exp2(q)),  q = -log2e * a  (computed directly by FMA chain)
//  - n-gate rows (wih/whh rows 4,5, biases 4,5) scaled by 2*log2(e):
//      tanh(g) = 1 - 2*rcp(exp2(G)+1), G = 2log2e * g = gin' + r*ghn'
struct GruW {
  float wr0, wr1, wr2, wr3;   // -log2e * wih rows 0,1
  float wz0, wz1, wz2, wz3;   // -log2e * wih rows 2,3
  float wn0, wn1, wn2, wn3;   // 2log2e * wih rows 4,5
  float ur0, ur1, ur2, ur3;   // -log2e * whh rows 0,1
  float uz0, uz1, uz2, uz3;   // -log2e * whh rows 2,3
  float un0, un1, un2, un3;   // 2log2e * whh rows 4,5
  float br0, br1, bz0, bz1;   // -log2e * (bih+bhh) rows 0..3
  float bin0, bin1;           // 2log2e * bih rows 4,5
  float bhn0, bhn1;           // 2log2e * bhh rows 4,5
};

#define NL2E (-1.4426950408889634f)
#define P2L2E (2.8853900817779268f)

__device__ __forceinline__ GruW load_gru(const float* __restrict__ wih,
                                         const float* __restrict__ whh,
                                         const float* __restrict__ bih,
                                         const float* __restrict__ bhh) {
  GruW g;
  g.wr0 = NL2E * wih[0];   g.wr1 = NL2E * wih[1];
  g.wr2 = NL2E * wih[2];   g.wr3 = NL2E * wih[3];
  g.wz0 = NL2E * wih[4];   g.wz1 = NL2E * wih[5];
  g.wz2 = NL2E * wih[6];   g.wz3 = NL2E * wih[7];
  g.wn0 = P2L2E * wih[8];  g.wn1 = P2L2E * wih[9];
  g.wn2 = P2L2E * wih[10]; g.wn3 = P2L2E * wih[11];
  g.ur0 = NL2E * whh[0];   g.ur1 = NL2E * whh[1];
  g.ur2 = NL2E * whh[2];   g.ur3 = NL2E * whh[3];
  g.uz0 = NL2E * whh[4];   g.uz1 = NL2E * whh[5];
  g.uz2 = NL2E * whh[6];   g.uz3 = NL2E * whh[7];
  g.un0 = P2L2E * whh[8];  g.un1 = P2L2E * whh[9];
  g.un2 = P2L2E * whh[10]; g.un3 = P2L2E * whh[11];
  g.br0 = NL2E * (bih[0] + bhh[0]); g.br1 = NL2E * (bih[1] + bhh[1]);
  g.bz0 = NL2E * (bih[2] + bhh[2]); g.bz1 = NL2E * (bih[3] + bhh[3]);
  g.bin0 = P2L2E * bih[4]; g.bin1 = P2L2E * bih[5];
  g.bhn0 = P2L2E * bhh[4]; g.bhn1 = P2L2E * bhh[5];
  return g;
}

__device__ __forceinline__ void cell(const GruW& g, float x0, float x1,
                                     float& h0, float& h1) {
  // pre-scaled gate pre-activations (q = -log2e * a)
  float qr0 = fmaf(g.wr0, x0, fmaf(g.wr1, x1, fmaf(g.ur0, h0, fmaf(g.ur1, h1, g.br0))));
  float qr1 = fmaf(g.wr2, x0, fmaf(g.wr3, x1, fmaf(g.ur2, h0, fmaf(g.ur3, h1, g.br1))));
  float qz0 = fmaf(g.wz0, x0, fmaf(g.wz1, x1, fmaf(g.uz0, h0, fmaf(g.uz1, h1, g.bz0))));
  float qz1 = fmaf(g.wz2, x0, fmaf(g.wz3, x1, fmaf(g.uz2, h0, fmaf(g.uz3, h1, g.bz1))));
  float r0 = frcp(1.0f + ex2(qr0));   // sigmoid; exp2 inf -> rcp -> 0 saturates
  float r1 = frcp(1.0f + ex2(qr1));
  float z0 = frcp(1.0f + ex2(qz0));
  float z1 = frcp(1.0f + ex2(qz1));

  // n-gate, pre-scaled by 2log2e
  float gin0 = fmaf(g.wn0, x0, fmaf(g.wn1, x1, g.bin0));
  float gin1 = fmaf(g.wn2, x0, fmaf(g.wn3, x1, g.bin1));
  float ghn0 = fmaf(g.un0, h0, fmaf(g.un1, h1, g.bhn0));
  float ghn1 = fmaf(g.un2, h0, fmaf(g.un3, h1, g.bhn1));
  float G0 = fmaf(r0, ghn0, gin0);
  float G1 = fmaf(r1, ghn1, gin1);
  float q0 = frcp(ex2(G0) + 1.0f);    // n = 1 - 2q
  float q1 = frcp(ex2(G1) + 1.0f);
  float n0 = fmaf(-2.0f, q0, 1.0f);
  float n1 = fmaf(-2.0f, q1, 1.0f);

  float d0 = h0 - n0;
  float d1 = h1 - n1;
  h0 = fmaf(z0, d0, n0);
  h1 = fmaf(z1, d1, n1);
}

// min-waves/EU = 4 -> 128-VGPR cap: whole row (19 xr + 14 hu + temps) stays
// register-resident; (256,8)'s 64-VGPR cap forced remat/spill traffic (R5:
// WRITE 78MB for a 29MB output) and mid-chain reload stalls.
__global__ __launch_bounds__(TPB, 4) void rec_policy_kernel(
    const float* __restrict__ x,
    const float* __restrict__ up_wih, const float* __restrict__ up_whh,
    const float* __restrict__ up_bih, const float* __restrict__ up_bhh,
    const float* __restrict__ down_wih, const float* __restrict__ down_whh,
    const float* __restrict__ down_bih, const float* __restrict__ down_bhh,
    const float* __restrict__ obs_w, const float* __restrict__ obs_b,
    const float* __restrict__ out_w, const float* __restrict__ out_b,
    float* __restrict__ out, int B) {
  const long row = (long)blockIdx.x * TPB + threadIdx.x;
  if (row >= B) return;

  // Uniform weight loads (pre-scaled) -> SGPRs where they fit.
  const GruW up = load_gru(up_wih, up_whh, up_bih, up_bhh);
  const GruW dn = load_gru(down_wih, down_whh, down_bih, down_bhh);
  const float ow0 = obs_w[0], ow1 = obs_w[1], ow2 = obs_w[2], ow3 = obs_w[3],
              ow4 = obs_w[4], ow5 = obs_w[5], ow6 = obs_w[6], ow7 = obs_w[7],
              ow8 = obs_w[8], ow9 = obs_w[9], ow10 = obs_w[10], ow11 = obs_w[11],
              ow12 = obs_w[12], ow13 = obs_w[13];
  const float ob0 = obs_b[0], ob1 = obs_b[1];
  const float vw0 = out_w[0], vw1 = out_w[1], vb = out_b[0];

  // Direct row load: 19 adjacent dwords -> merged dwordx4s; all kept in VGPRs.
  const float* __restrict__ xp = x + row * 19;
  float xr0 = xp[0],  xr1 = xp[1],  xr2 = xp[2],  xr3 = xp[3],  xr4 = xp[4];
  float xr5 = xp[5],  xr6 = xp[6],  xr7 = xp[7],  xr8 = xp[8],  xr9 = xp[9];
  float xr10 = xp[10], xr11 = xp[11], xr12 = xp[12], xr13 = xp[13];
  float xr14 = xp[14], xr15 = xp[15], xr16 = xp[16], xr17 = xp[17], xr18 = xp[18];

  // ---- up GRU, 7 steps ----
  float h0 = 0.f, h1 = 0.f;
  float hu0, hu1, hu2, hu3, hu4, hu5, hu6, hu7, hu8, hu9, hu10, hu11, hu12, hu13;
  cell(up, xr5,  xr12, h0, h1); hu0 = h0;  hu1 = h1;
  cell(up, xr6,  xr13, h0, h1); hu2 = h0;  hu3 = h1;
  cell(up, xr7,  xr14, h0, h1); hu4 = h0;  hu5 = h1;
  cell(up, xr8,  xr15, h0, h1); hu6 = h0;  hu7 = h1;
  cell(up, xr9,  xr16, h0, h1); hu8 = h0;  hu9 = h1;
  cell(up, xr10, xr17, h0, h1); hu10 = h0; hu11 = h1;
  cell(up, xr11, xr18, h0, h1); hu12 = h0; hu13 = h1;

  // ---- obs linear (unscaled weights) ----
  float a0 = fmaf(xr0, ow0, fmaf(xr1, ow1, fmaf(xr2, ow2, fmaf(xr3, ow3,
             fmaf(xr4, ow4, fmaf(hu12, ow5, fmaf(hu13, ow6, ob0)))))));
  float a1 = fmaf(xr0, ow7, fmaf(xr1, ow8, fmaf(xr2, ow9, fmaf(xr3, ow10,
             fmaf(xr4, ow11, fmaf(hu12, ow12, fmaf(hu13, ow13, ob1)))))));
  h0 = a0; h1 = a1;

  // ---- down GRU, 7 steps + per-step output ----
  float* __restrict__ po = out + row * 7;
  float o0, o1, o2, o3, o4, o5, o6;
  cell(dn, hu0,  hu1,  h0, h1); o0 = fmaf(vw0, h0, fmaf(vw1, h1, vb));
  cell(dn, hu2,  hu3,  h0, h1); o1 = fmaf(vw0, h0, fmaf(vw1, h1, vb));
  cell(dn, hu4,  hu5,  h0, h1); o2 = fmaf(vw0, h0, fmaf(vw1, h1, vb));
  cell(dn, hu6,  hu7,  h0, h1); o3 = fmaf(vw0, h0, fmaf(vw1, h1, vb));
  cell(dn, hu8,  hu9,  h0, h1); o4 = fmaf(vw0, h0, fmaf(vw1, h1, vb));
  cell(dn, hu10, hu11, h0, h1); o5 = fmaf(vw0, h0, fmaf(vw1, h1, vb));
  cell(dn, hu12, hu13, h0, h1); o6 = fmaf(vw0, h0, fmaf(vw1, h1, vb));
  po[0] = o0; po[1] = o1; po[2] = o2; po[3] = o3;
  po[4] = o4; po[5] = o5; po[6] = o6;
}

extern "C" void kernel_launch(void* const* d_in, const int* in_sizes, int n_in,
                              void* d_out, int out_size, void* d_ws, size_t ws_size,
                              hipStream_t stream) {
  const float* x        = (const float*)d_in[0];
  const float* up_wih   = (const float*)d_in[1];
  const float* up_whh   = (const float*)d_in[2];
  const float* up_bih   = (const float*)d_in[3];
  const float* up_bhh   = (const float*)d_in[4];
  const float* down_wih = (const float*)d_in[5];
  const float* down_whh = (const float*)d_in[6];
  const float* down_bih = (const float*)d_in[7];
  const float* down_bhh = (const float*)d_in[8];
  const float* obs_w    = (const float*)d_in[9];
  const float* obs_b    = (const float*)d_in[10];
  const float* out_w    = (const float*)d_in[11];
  const float* out_b    = (const float*)d_in[12];
  float* out = (float*)d_out;

  const int B = in_sizes[0] / 19;
  const int blocks = (B + TPB - 1) / TPB;
  rec_policy_kernel<<<blocks, TPB, 0, stream>>>(
      x, up_wih, up_whh, up_bih, up_bhh, down_wih, down_whh, down_bih, down_bhh,
      obs_w, obs_b, out_w, out_b, out, B);
}